// Round 8
// baseline (3035.530 us; speedup 1.0000x reference)
//
#include <hip/hip_runtime.h>
#include <stdint.h>

// LSTM: BATCH=64, SEQ=512, INPUT=512, UNITS=512, gates i,f,g,o.
// R5-R11: exchange-semantics sweep (poll shape, flags, local mailbox, atomics
//   +/-sc1, nt) -- ALL null/regressed. Conclusion: publish->detect visibility
//   is ~4-6k cy of far-memory latency (H traffic shows in WRITE_SIZE => DRAM
//   class), irreducible at instruction level. R6 calibrated: zero slack, added
//   RTs cost 1:1.
// R12: AMORTIZE the latency instead. Each block time-multiplexes TWO batch
//   groups (sA=p, sB=p+4) through one loop: group B's full compute runs while
//   group A's publish is in flight, and vice versa. Per-group mailbox protocol
//   is byte-identical to the verified baseline (disjoint batch rows => disjoint
//   slots; same tags/parity/WAR pipeline argument). Weights (128 VGPR) shared
//   across groups. Grid 256->128 blocks; poll contention halves.
//   Period model: C+V per step -> 2C+max(0,V-C) per TWO steps (~2x).

#define OFF_XBF   0ull                    // bf16 x [64][512][512]  (32 MB)
#define OFF_HU    33562624ull             // u64 H[2][64][256]: (tag<<32)|bf16pair

typedef short short8 __attribute__((ext_vector_type(8)));
typedef float f32x4 __attribute__((ext_vector_type(4)));
typedef unsigned u32x4 __attribute__((ext_vector_type(4)));

__device__ __forceinline__ unsigned f32_to_bf16(float f) {
    union { float f; unsigned u; } v; v.f = f;
    unsigned u = v.u;
    unsigned r = u + 0x7FFFu + ((u >> 16) & 1u);   // RNE
    return r >> 16;
}

__global__ void prep_kernel(const float* __restrict__ x,
                            const float* __restrict__ h0,
                            unsigned char* __restrict__ ws) {
    long long i = (long long)blockIdx.x * blockDim.x + threadIdx.x;
    if (i < 2097152) {   // x -> bf16, 8 elements/thread
        const float4* xs = (const float4*)x + i * 2;
        float4 a = xs[0], b = xs[1];
        unsigned w0 = f32_to_bf16(a.x) | (f32_to_bf16(a.y) << 16);
        unsigned w1 = f32_to_bf16(a.z) | (f32_to_bf16(a.w) << 16);
        unsigned w2 = f32_to_bf16(b.x) | (f32_to_bf16(b.y) << 16);
        unsigned w3 = f32_to_bf16(b.z) | (f32_to_bf16(b.w) << 16);
        uint4 o; o.x = w0; o.y = w1; o.z = w2; o.w = w3;
        ((uint4*)(ws + OFF_XBF))[i] = o;
        return;
    }
    i -= 2097152;
    if (i < 16384) {     // H[0] <- h0, tag=1
        int b = (int)(i >> 8), p = (int)(i & 255);
        unsigned lo = f32_to_bf16(h0[b * 512 + 2 * p]);
        unsigned hi = f32_to_bf16(h0[b * 512 + 2 * p + 1]);
        ((unsigned long long*)(ws + OFF_HU))[(long long)b * 256 + p] =
            (unsigned long long)(lo | (hi << 16)) | (1ull << 32);
    }
}

// Wide data poll: 4x dwordx4 sc0/sc1 over this thread's contiguous 64B region;
// per-u64 tags verified.
#define SPIN_LOAD(BASEPTR, TAGV, H0V, H1V)                                     \
    {                                                                          \
        u32x4 p0, p1, p2, p3;                                                  \
        for (;;) {                                                             \
            asm volatile(                                                      \
                "global_load_dwordx4 %0, %4, off sc0 sc1\n\t"                  \
                "global_load_dwordx4 %1, %4, off offset:16 sc0 sc1\n\t"        \
                "global_load_dwordx4 %2, %4, off offset:32 sc0 sc1\n\t"        \
                "global_load_dwordx4 %3, %4, off offset:48 sc0 sc1\n\t"        \
                "s_waitcnt vmcnt(0)"                                           \
                : "=v"(p0), "=v"(p1), "=v"(p2), "=v"(p3)                       \
                : "v"(BASEPTR)                                                 \
                : "memory");                                                   \
            unsigned bad = (p0.y ^ (TAGV)) | (p0.w ^ (TAGV))                   \
                         | (p1.y ^ (TAGV)) | (p1.w ^ (TAGV))                   \
                         | (p2.y ^ (TAGV)) | (p2.w ^ (TAGV))                   \
                         | (p3.y ^ (TAGV)) | (p3.w ^ (TAGV));                  \
            if (!bad) {                                                        \
                H0V.x = p0.x; H0V.y = p0.z; H0V.z = p1.x; H0V.w = p1.z;        \
                H1V.x = p2.x; H1V.y = p2.z; H1V.z = p3.x; H1V.w = p3.z;        \
                break;                                                         \
            }                                                                  \
            __builtin_amdgcn_s_sleep(0);                                       \
        }                                                                      \
    }

// 16-step K-loop MFMA: acc = A(LDS rows 0..7, zero-padded) @ W
#define MFMA_LOOP(AP, W, ACC)                                                  \
    {                                                                          \
        f32x4 a0_ = {0.f,0.f,0.f,0.f}, a1_ = {0.f,0.f,0.f,0.f};                \
        _Pragma("unroll")                                                      \
        for (int kt = 0; kt < 16; kt += 2) {                                   \
            short8 v0_ = (nl < 8) ? *(const short8*)((AP) + kt * 64) : zfrag;  \
            short8 v1_ = (nl < 8) ? *(const short8*)((AP) + kt * 64 + 64) : zfrag; \
            a0_ = __builtin_amdgcn_mfma_f32_16x16x32_bf16(v0_, (W)[kt], a0_, 0, 0, 0); \
            a1_ = __builtin_amdgcn_mfma_f32_16x16x32_bf16(v1_, (W)[kt + 1], a1_, 0, 0, 0); \
        }                                                                      \
        ACC = a0_ + a1_;                                                       \
    }

// Gate fusion + tagged publish for one group (SS = group's s index)
#define GATES_PUBLISH(ACCX, ACCH, CR, LDSOUT, SS)                              \
    {                                                                          \
        float hn[4]; unsigned hb[4];                                           \
        _Pragma("unroll")                                                      \
        for (int r = 0; r < 4; ++r) {                                          \
            float zs = (ACCX)[r] + (ACCH)[r];                                  \
            float z0 = __shfl(zs, sl0, 64) + bi;                               \
            float z1 = __shfl(zs, sl1, 64) + bf_;                              \
            float z2 = __shfl(zs, sl2, 64) + bg;                               \
            float z3 = __shfl(zs, sl3, 64) + bo;                               \
            float ig = __fdividef(1.f, 1.f + __expf(-z0));                     \
            float fg = __fdividef(1.f, 1.f + __expf(-z1));                     \
            float z2c = fminf(fmaxf(z2, -20.f), 20.f);                         \
            float e2 = __expf(2.f * z2c);                                      \
            float gg = __fdividef(e2 - 1.f, e2 + 1.f);                         \
            float og = __fdividef(1.f, 1.f + __expf(-z3));                     \
            float cn = fg * (CR)[r] + ig * gg;                                 \
            (CR)[r] = cn;                                                      \
            float cnc = fminf(fmaxf(cn, -20.f), 20.f);                         \
            float ec = __expf(2.f * cnc);                                      \
            hn[r] = og * __fdividef(ec - 1.f, ec + 1.f);                       \
            hb[r] = f32_to_bf16(hn[r]);                                        \
        }                                                                      \
        unsigned oth[4];                                                       \
        _Pragma("unroll")                                                      \
        for (int r = 0; r < 4; ++r)                                            \
            oth[r] = (unsigned)__shfl((int)hb[r], lane ^ 1, 64);               \
        if (q < 2 && g == 0) {                                                 \
            _Pragma("unroll")                                                  \
            for (int r = 0; r < 4; ++r)                                        \
                (LDSOUT)[(t & 7) * 128 + (q * 4 + r) * 16 + wave * 4 + up] = hn[r]; \
            if ((up & 1) == 0) {                                               \
                _Pragma("unroll")                                              \
                for (int r = 0; r < 4; ++r) {                                  \
                    unsigned long long v = (unsigned long long)(hb[r] | (oth[r] << 16)) \
                                         | ((unsigned long long)(unsigned)(t + 2) << 32); \
                    unsigned long long* pp = Hu + (size_t)wb * 16384           \
                                           + (size_t)(8 * (SS) + q * 4 + r) * 256 \
                                           + jg * 8 + wave * 2 + (up >> 1);    \
                    asm volatile("global_store_dwordx2 %0, %1, off sc0 sc1"    \
                                 :: "v"(pp), "v"(v) : "memory");               \
                }                                                              \
            }                                                                  \
        }                                                                      \
    }

#define OUT_BURST(LDSOUT, SS)                                                  \
    {                                                                          \
        const int stp = tid >> 5, brow = (tid >> 2) & 7, qd = tid & 3;         \
        float4 v = *(const float4*)((LDSOUT) + stp * 128 + brow * 16 + qd * 4); \
        *(float4*)(out + (long long)(t - 7 + stp) * 32768                      \
                       + (8 * (SS) + brow) * 512 + jg * 16 + qd * 4) = v;      \
    }

// LDS: xbufA [8][1040] @0, xbufB @8320, hbufA @16640, hbufB @24960,
//      outA ring @33280 (4KB), outB ring @37376 (4KB). Total 41472 B.
__launch_bounds__(256, 1)
__global__ void lstm_kernel(const float* __restrict__ c0,
                            const float* __restrict__ bias,
                            const float* __restrict__ Wx,
                            const float* __restrict__ Wh,
                            float* __restrict__ out,
                            unsigned char* __restrict__ ws) {
    const int tid  = threadIdx.x;
    const int p    = blockIdx.x >> 5;   // group-pair 0..3
    const int jg   = blockIdx.x & 31;   // unit group: units 16jg..16jg+15
    const int sA   = p;                 // batches 8p..8p+7
    const int sB   = p + 4;             // batches 8p+32..8p+39
    const int lane = tid & 63;
    const int wave = tid >> 6;
    const int nl   = lane & 15;
    const int q    = lane >> 4;
    const int up   = nl & 3;
    const int g    = nl >> 2;

    const unsigned short* xbf = (const unsigned short*)(ws + OFF_XBF);
    unsigned long long* Hu = (unsigned long long*)(ws + OFF_HU);

    __shared__ __align__(16) unsigned char lds[41472];
    float* lds_outA = (float*)(lds + 33280);
    float* lds_outB = (float*)(lds + 37376);

    // persistent weight fragments, SHARED by both groups (same unit columns)
    const int ncol = g * 512 + jg * 16 + wave * 4 + up;
    short8 fWh[16], fWx[16];
#pragma unroll
    for (int kt = 0; kt < 16; ++kt) {
        const int k0 = kt * 32 + q * 8;
        short8 vh, vx;
#pragma unroll
        for (int j = 0; j < 8; ++j) {
            vh[j] = (short)f32_to_bf16(Wh[(long long)(k0 + j) * 2048 + ncol]);
            vx[j] = (short)f32_to_bf16(Wx[(long long)(k0 + j) * 2048 + ncol]);
        }
        fWh[kt] = vh; fWx[kt] = vx;
    }

    const int ub = jg * 16 + wave * 4 + up;
    const float bi  = bias[ub];
    const float bf_ = bias[512 + ub];
    const float bg  = bias[1024 + ub];
    const float bo  = bias[1536 + ub];

    float crA[4], crB[4];
#pragma unroll
    for (int r = 0; r < 4; ++r) {
        const int m = q * 4 + r;
        crA[r] = (q < 2) ? c0[(8 * sA + m) * 512 + ub] : 0.f;
        crB[r] = (q < 2) ? c0[(8 * sB + m) * 512 + ub] : 0.f;
    }

    // staging map: thread -> (row sm, 64B chunk sc) of each 8x512 slice
    const int sm = tid >> 5, sc = tid & 31;
    const int sbA = 8 * sA + sm, sbB = 8 * sB + sm;
    const unsigned* xsrcA = (const unsigned*)xbf + (long long)sbA * 131072 + sc * 8;
    const unsigned* xsrcB = (const unsigned*)xbf + (long long)sbB * 131072 + sc * 8;
    unsigned long long* hsrcA = Hu + sbA * 256 + sc * 8;
    unsigned long long* hsrcB = Hu + sbB * 256 + sc * 8;
    uint4* xdstA = (uint4*)(lds + sm * 1040 + sc * 32);
    uint4* xdstB = (uint4*)(lds + 8320 + sm * 1040 + sc * 32);
    uint4* hdstA = (uint4*)(lds + 16640 + sm * 1040 + sc * 32);
    uint4* hdstB = (uint4*)(lds + 24960 + sm * 1040 + sc * 32);

    const unsigned char* axpA = lds + nl * 1040 + q * 16;
    const unsigned char* axpB = lds + 8320 + nl * 1040 + q * 16;
    const unsigned char* ahpA = lds + 16640 + nl * 1040 + q * 16;
    const unsigned char* ahpB = lds + 24960 + nl * 1040 + q * 16;
    const short8 zfrag = {0, 0, 0, 0, 0, 0, 0, 0};

    const int gbase = (lane & 0x30) | (lane & 3);
    const int sl0 = gbase, sl1 = gbase | 4, sl2 = gbase | 8, sl3 = gbase | 12;

    // ---- prologue: stage x(0) both groups, accx both, spin h0 both ----
    uint4 pA0 = *(const uint4*)(xsrcA);
    uint4 pA1 = *(const uint4*)(xsrcA + 4);
    uint4 pB0 = *(const uint4*)(xsrcB);
    uint4 pB1 = *(const uint4*)(xsrcB + 4);
    xdstA[0] = pA0; xdstA[1] = pA1;
    xdstB[0] = pB0; xdstB[1] = pB1;
    pA0 = *(const uint4*)(xsrcA + 256); pA1 = *(const uint4*)(xsrcA + 260);
    pB0 = *(const uint4*)(xsrcB + 256); pB1 = *(const uint4*)(xsrcB + 260);
    __syncthreads();

    f32x4 accxA, accxB;
    MFMA_LOOP(axpA, fWx, accxA);
    MFMA_LOOP(axpB, fWx, accxB);
    {
        uint4 h0v, h1v;
        SPIN_LOAD((const unsigned char*)hsrcA, 1u, h0v, h1v);
        hdstA[0] = h0v; hdstA[1] = h1v;
    }
    {
        uint4 h0v, h1v;
        SPIN_LOAD((const unsigned char*)hsrcB, 1u, h0v, h1v);
        hdstB[0] = h0v; hdstB[1] = h1v;
    }
    __syncthreads();

    for (int t = 0; t < 512; ++t) {
        const int wb = (t + 1) & 1;

        // ---- group A: h-MFMA -> gates -> publish (exchange A in flight) ----
        {
            f32x4 acch;
            MFMA_LOOP(ahpA, fWh, acch);
            GATES_PUBLISH(accxA, acch, crA, lds_outA, sA);
        }

        // ---- group B: h-MFMA -> gates -> publish (covers A's transit) ----
        {
            f32x4 acch;
            MFMA_LOOP(ahpB, fWh, acch);
            GATES_PUBLISH(accxB, acch, crB, lds_outB, sB);
        }

        // ---- stage x(t+1) both groups; issue prefetch t+2 ----
        xdstA[0] = pA0; xdstA[1] = pA1;
        xdstB[0] = pB0; xdstB[1] = pB1;
        {
            const int tp = (t + 2 < 512) ? (t + 2) : 511;
            pA0 = *(const uint4*)(xsrcA + tp * 256);
            pA1 = *(const uint4*)(xsrcA + tp * 256 + 4);
            pB0 = *(const uint4*)(xsrcB + tp * 256);
            pB1 = *(const uint4*)(xsrcB + tp * 256 + 4);
        }
        __syncthreads();   // S0

        // out bursts every 8 steps
        if ((t & 7) == 7) {
            OUT_BURST(lds_outA, sA);
            OUT_BURST(lds_outB, sB);
        }

        // ---- x-MFMA both groups (more cover for the exchanges) ----
        MFMA_LOOP(axpA, fWx, accxA);
        MFMA_LOOP(axpB, fWx, accxB);

        // ---- spins: A (longest in flight) then B ----
        {
            const unsigned char* hs = (const unsigned char*)hsrcA
                                    + (size_t)wb * 131072;
            const unsigned tag = (unsigned)(t + 2);
            uint4 h0v, h1v;
            SPIN_LOAD(hs, tag, h0v, h1v);
            hdstA[0] = h0v; hdstA[1] = h1v;
        }
        {
            const unsigned char* hs = (const unsigned char*)hsrcB
                                    + (size_t)wb * 131072;
            const unsigned tag = (unsigned)(t + 2);
            uint4 h0v, h1v;
            SPIN_LOAD(hs, tag, h0v, h1v);
            hdstB[0] = h0v; hdstB[1] = h1v;
        }
        __syncthreads();   // S1
    }
}

extern "C" void kernel_launch(void* const* d_in, const int* in_sizes, int n_in,
                              void* d_out, int out_size, void* d_ws, size_t ws_size,
                              hipStream_t stream) {
    const float* x  = (const float*)d_in[0];
    const float* h0 = (const float*)d_in[1];
    const float* c0 = (const float*)d_in[2];
    const float* Wx = (const float*)d_in[3];
    const float* Wh = (const float*)d_in[4];
    const float* b  = (const float*)d_in[5];
    unsigned char* ws = (unsigned char*)d_ws;
    float* out = (float*)d_out;

    const long long n0 = 2097152 + 16384;
    const int blocks0 = (int)((n0 + 255) / 256);
    hipLaunchKernelGGL(prep_kernel, dim3(blocks0), dim3(256), 0, stream, x, h0, ws);
    hipLaunchKernelGGL(lstm_kernel, dim3(128), dim3(256), 0, stream,
                       c0, b, Wx, Wh, out, ws);
}